// Round 6
// baseline (101.591 us; speedup 1.0000x reference)
//
#include <hip/hip_runtime.h>

// 601-node DAG scan — see round-3 notes. Kernel body unchanged (verified
// absmax=0.0 at 1x in round 4). TIMING DIAGNOSTIC RETRY (round-5 run died to
// a transient container failure before executing): kernel_launch launches the
// identical kernel 4x back-to-back (same deterministic work each time, same
// output value rewritten — graph-capture-safe, correctness-neutral).
// dur_us_new = 71.2 + 3*T_kernel + ~6us dispatch overhead, which
// disambiguates T_kernel from the ~70us of harness poison-fill/replay
// overhead dominating dur_us (top-5 dispatches are all 39us 256MB
// fillBuffer at 85% HBM peak; dag_kernel absent from top-5 => <39us).

#define NUM_IN  100
#define NUM_HID 501
#define TOTAL   601

__launch_bounds__(64, 1)
__global__ void dag_kernel(const float* __restrict__ x,
                           const float* __restrict__ w_in,
                           const float* __restrict__ b_in,
                           const float* __restrict__ w_hid,
                           const float* __restrict__ b_hid,
                           const int*   __restrict__ edge_idx,
                           float* __restrict__ out) {
    __shared__ float vals[TOTAL];
    const int lane = threadIdx.x;  // 0..63, single wave

    // ---- prefetch per-owned-node params (8 nodes/lane, strided) ----
#define LOADP(J)                                                              \
    int4   e##J = make_int4(0, 0, 0, 0);                                      \
    float4 w##J = make_float4(0.f, 0.f, 0.f, 0.f);                            \
    float  b##J = 0.f;                                                        \
    bool   d##J;                                                              \
    {                                                                         \
        int k = (J) * 64 + lane;                                              \
        d##J = (k >= NUM_HID); /* out-of-range slots are born "done" */       \
        if (k < NUM_HID) {                                                    \
            e##J = ((const int4*)edge_idx)[k];                                \
            w##J = ((const float4*)w_hid)[k];                                 \
            b##J = b_hid[k];                                                  \
        }                                                                     \
    }

    LOADP(0) LOADP(1) LOADP(2) LOADP(3) LOADP(4) LOADP(5) LOADP(6) LOADP(7)

    // ---- input nodes (overlap the prefetch latency window) ----
    {
        float s = fmaf(w_in[lane], x[lane], b_in[lane]);
        vals[lane] = __builtin_amdgcn_rcpf(1.0f + __expf(-s));
    }
    if (lane < NUM_IN - 64) {
        int i = 64 + lane;
        float s = fmaf(w_in[i], x[i], b_in[i]);
        vals[i] = __builtin_amdgcn_rcpf(1.0f + __expf(-s));
    }
    // ---- hidden sentinels ----
    #pragma unroll
    for (int j = 0; j < 8; ++j) {
        int kk = j * 64 + lane;
        if (kk < NUM_HID) vals[NUM_IN + kk] = -1.0f;
    }
    __builtin_amdgcn_wave_barrier();  // compile-time ordering guard (free)

    // ---- one slot visit: skip if slot fully done; else gather 4 preds,
    //      complete node iff all preds ready (ready == all sign bits clear). --
#define SLOT(J)                                                               \
    if (!__all((int)d##J)) {                                                  \
        if (!d##J) {                                                          \
            float v0 = vals[e##J.x];                                          \
            float v1 = vals[e##J.y];                                          \
            float v2 = vals[e##J.z];                                          \
            float v3 = vals[e##J.w];                                          \
            int ready = ~((__float_as_int(v0) | __float_as_int(v1) |          \
                           __float_as_int(v2) | __float_as_int(v3))) >> 31;   \
            if (ready & 1) {                                                  \
                float s = fmaf(w##J.x, v0,                                    \
                          fmaf(w##J.y, v1,                                    \
                          fmaf(w##J.z, v2,                                    \
                          fmaf(w##J.w, v3, b##J))));                          \
                vals[NUM_IN + (J) * 64 + lane] =                              \
                    __builtin_amdgcn_rcpf(1.0f + __expf(-s));                 \
                d##J = true;                                                  \
            }                                                                 \
        }                                                                     \
    }                                                                         \
    __builtin_amdgcn_wave_barrier();

    // ---- ordered sweeps; expected ~3-4, hard bound 64 ----
    bool alldone = false;
    #pragma unroll 1
    for (int sw = 0; sw < 64 && !alldone; ++sw) {
        SLOT(0) SLOT(1) SLOT(2) SLOT(3) SLOT(4) SLOT(5) SLOT(6) SLOT(7)
        alldone = __all((int)(d0 & d1 & d2 & d3 & d4 & d5 & d6 & d7));
    }

    if (lane == 0) out[0] = vals[TOTAL - 1];
}

extern "C" void kernel_launch(void* const* d_in, const int* in_sizes, int n_in,
                              void* d_out, int out_size, void* d_ws, size_t ws_size,
                              hipStream_t stream) {
    (void)in_sizes; (void)n_in; (void)out_size; (void)d_ws; (void)ws_size;
    const float* x     = (const float*)d_in[0];
    const float* w_in  = (const float*)d_in[1];
    const float* b_in  = (const float*)d_in[2];
    const float* w_hid = (const float*)d_in[3];
    const float* b_hid = (const float*)d_in[4];
    const int*   eidx  = (const int*)d_in[5];
    float*       out   = (float*)d_out;

    // DIAGNOSTIC: 4 identical launches. Delta vs round-4's single launch
    // (71.2us) gives 3*T_kernel directly. Revert to 1 launch next round.
    dag_kernel<<<dim3(1), dim3(64), 0, stream>>>(x, w_in, b_in, w_hid, b_hid,
                                                 eidx, out);
    dag_kernel<<<dim3(1), dim3(64), 0, stream>>>(x, w_in, b_in, w_hid, b_hid,
                                                 eidx, out);
    dag_kernel<<<dim3(1), dim3(64), 0, stream>>>(x, w_in, b_in, w_hid, b_hid,
                                                 eidx, out);
    dag_kernel<<<dim3(1), dim3(64), 0, stream>>>(x, w_in, b_in, w_hid, b_hid,
                                                 eidx, out);
}

// Round 10
// 66.281 us; speedup vs baseline: 1.5327x; 1.5327x over previous
//
#include <hip/hip_runtime.h>

// 601-node DAG scan:
//   nodes 0..99 : sigmoid(w_in[i]*x[i] + b_in[i])
//   nodes 100+k : sigmoid(dot4(w_hid[k], vals[edge_idx[k]]) + b_hid[k]),
//                 edge_idx[k][j] < 100+k   (strictly backward edges)
//   output      : vals[600]
//
// Measured r4/r6: T_kernel+dispatch ~= 10.1 us/launch vs ~61 us fixed harness
// poison/restore inside the timed region. Single-wave kernel => cold I-cache
// misses are serial; prior macro-expanded kernel was ~3 KB. Code-size attack:
// params in LDS (runtime-indexable, unlike registers), staged via
// global_load_lds DMA from a compact non-unrolled loop (24 DMAs in one
// latency window, overlapped with input-node compute). Solve = runtime loop
// over 8 slots, each to local fixpoint (one ordered pass completes the DAG:
// every pred of a slot-J node is in an earlier slot — final — or earlier in
// J). Termination: each fixpoint iter completes at least the lowest-index
// unfinished node. Resubmit (4x GPU acquisition timeouts; never executed).
// Audited: DMA dest linearity (wave-uniform base + lane*size, matches
// source rows), literal size args, tail clamp into 512-row padding, vmcnt
// drain via __syncthreads before first param read, sentinel coverage
// 100..600 complete, per-slot fixpoint termination.
//
// One wave; vals sentinel -1.0f = "not ready" (sigmoid outputs in [0,1]).
// Intra-wave LDS ordering = program order (no s_barrier needed in solve).

#define NUM_IN  100
#define NUM_HID 501
#define TOTAL   601

__launch_bounds__(64, 1)
__global__ void dag_kernel(const float* __restrict__ x,
                           const float* __restrict__ w_in,
                           const float* __restrict__ b_in,
                           const float* __restrict__ w_hid,
                           const float* __restrict__ b_hid,
                           const int*   __restrict__ edge_idx,
                           float* __restrict__ out) {
    __shared__ __align__(16) float  vals[TOTAL];
    __shared__ __align__(16) int4   eL[512];   // 8 KB (501 used + pad)
    __shared__ __align__(16) float4 wL[512];   // 8 KB
    __shared__ __align__(16) float  bL[512];   // 2 KB
    const int lane = threadIdx.x;  // 0..63, single wave

    // ---- stage params global->LDS via DMA; tight loop, all 24 in flight ----
    #pragma unroll 1
    for (int j = 0; j < 8; ++j) {
        int k  = j * 64 + lane;
        int ks = k < NUM_HID ? k : NUM_HID - 1;  // clamp; dup lands in pad
        __builtin_amdgcn_global_load_lds(
            (const __attribute__((address_space(1))) void*)(edge_idx + ks * 4),
            (__attribute__((address_space(3))) void*)(eL + j * 64), 16, 0, 0);
        __builtin_amdgcn_global_load_lds(
            (const __attribute__((address_space(1))) void*)(w_hid + ks * 4),
            (__attribute__((address_space(3))) void*)(wL + j * 64), 16, 0, 0);
        __builtin_amdgcn_global_load_lds(
            (const __attribute__((address_space(1))) void*)(b_hid + ks),
            (__attribute__((address_space(3))) void*)(bL + j * 64), 4, 0, 0);
    }

    // ---- input nodes + sentinels (overlap the DMA latency window) ----
    {
        float s = fmaf(w_in[lane], x[lane], b_in[lane]);
        vals[lane] = __builtin_amdgcn_rcpf(1.0f + __expf(-s));
    }
    if (lane < NUM_IN - 64) {
        int i = 64 + lane;
        float s = fmaf(w_in[i], x[i], b_in[i]);
        vals[i] = __builtin_amdgcn_rcpf(1.0f + __expf(-s));
    }
    {   // sentinels: vals[100..599] as float4, vals[600] scalar
        float4* vp = (float4*)(vals + NUM_IN);  // byte 400, 16B-aligned
        const float4 m1 = make_float4(-1.f, -1.f, -1.f, -1.f);
        vp[lane] = m1;
        if (lane < 61) vp[64 + lane] = m1;
        if (lane == 0) vals[TOTAL - 1] = -1.0f;
    }

    // single-wave s_barrier is cheap; emits s_waitcnt vmcnt(0) lgkmcnt(0)
    // -> DMA-staged params guaranteed visible in LDS.
    __syncthreads();

    // ---- solve: 8 slots in order, each Jacobi-iterated to local fixpoint ----
    #pragma unroll 1
    for (int j = 0; j < 8; ++j) {
        int  k    = j * 64 + lane;
        bool done = (k >= NUM_HID);
        int4   e = make_int4(0, 0, 0, 0);
        float4 w = make_float4(0.f, 0.f, 0.f, 0.f);
        float  b = 0.f;
        if (!done) { e = eL[k]; w = wL[k]; b = bL[k]; }
        while (!__all((int)done)) {
            if (!done) {
                float v0 = vals[e.x];
                float v1 = vals[e.y];
                float v2 = vals[e.z];
                float v3 = vals[e.w];
                int ns = __float_as_int(v0) | __float_as_int(v1) |
                         __float_as_int(v2) | __float_as_int(v3);
                if (ns >= 0) {  // all sign bits clear -> all preds ready
                    float s = fmaf(w.x, v0,
                              fmaf(w.y, v1,
                              fmaf(w.z, v2,
                              fmaf(w.w, v3, b))));
                    vals[NUM_IN + k] =
                        __builtin_amdgcn_rcpf(1.0f + __expf(-s));
                    done = true;
                }
            }
            __builtin_amdgcn_wave_barrier();  // free compile-time guard
        }
    }

    // node 600 written in slot 7 by lane 52; same-wave program order makes it
    // visible to lane 0 here.
    if (lane == 0) out[0] = vals[TOTAL - 1];
}

extern "C" void kernel_launch(void* const* d_in, const int* in_sizes, int n_in,
                              void* d_out, int out_size, void* d_ws, size_t ws_size,
                              hipStream_t stream) {
    (void)in_sizes; (void)n_in; (void)out_size; (void)d_ws; (void)ws_size;
    const float* x     = (const float*)d_in[0];
    const float* w_in  = (const float*)d_in[1];
    const float* b_in  = (const float*)d_in[2];
    const float* w_hid = (const float*)d_in[3];
    const float* b_hid = (const float*)d_in[4];
    const int*   eidx  = (const int*)d_in[5];
    float*       out   = (float*)d_out;

    dag_kernel<<<dim3(1), dim3(64), 0, stream>>>(x, w_in, b_in, w_hid, b_hid,
                                                 eidx, out);
}